// Round 9
// baseline (233.708 us; speedup 1.0000x reference)
//
#include <hip/hip_runtime.h>
#include <math.h>

#define N_NODES 50000
#define N_EDGES 800000
#define D 64
#define N_GRAPHS 512
#define N_CLASSES 10
#define NT 3125        // 16-row tiles
#define NPART 6250     // nodes per XCD partition (50000/8)
#define MLP_BLOCKS 196 // 784 waves, 4 tiles/wave, stride 784

#define SCAN_B 512
#define NB_SCAN ((N_NODES + SCAN_B - 1) / SCAN_B)  // 98

typedef __attribute__((ext_vector_type(8))) short bf16x8;
typedef __attribute__((ext_vector_type(4))) float f32x4;

#define MFMA16(a, b, c) __builtin_amdgcn_mfma_f32_16x16x32_bf16(a, b, c, 0, 0, 0)

// ---------------- helpers ----------------

__device__ __forceinline__ unsigned mapf(float f) {
  unsigned u = __float_as_uint(f);
  return (u & 0x80000000u) ? ~u : (u | 0x80000000u);
}
__device__ __forceinline__ float unmapf(unsigned u) {
  return __uint_as_float((u & 0x80000000u) ? (u & 0x7FFFFFFFu) : ~u);
}
__device__ __forceinline__ ushort bf16_rne(float f) {
  unsigned u = __float_as_uint(f);
  u += 0x7FFFu + ((u >> 16) & 1u);
  return (ushort)(u >> 16);
}
__device__ __forceinline__ float bf16_tof(ushort h) {
  return __uint_as_float(((unsigned)h) << 16);
}
__device__ __forceinline__ unsigned pack2(float a, float b) {
  return (unsigned)bf16_rne(a) | ((unsigned)bf16_rne(b) << 16);
}
__device__ __forceinline__ float2 unpack2(unsigned v) {
  return make_float2(__uint_as_float(v << 16), __uint_as_float(v & 0xFFFF0000u));
}

// ---------------- x -> bf16 ----------------

__global__ void to_bf16(const float* __restrict__ in, unsigned* __restrict__ out) {
  int i = blockIdx.x * 256 + threadIdx.x;
  float4 v = reinterpret_cast<const float4*>(in)[i];
  reinterpret_cast<uint2*>(out)[i] = make_uint2(pack2(v.x, v.y), pack2(v.z, v.w));
}

// ---------------- weight fragment prep (hi/lo split) ----------------
// wf layout (ushorts): per layer 16384: W1hi@0, W1lo@4096, W2hi@8192, W2lo@12288.
// within region: frag f (8), lane (64), v (8): off = f*512 + lane*8 + v
// value = W[k][n], k = (f&1)*32 + (lane>>4)*8 + v, n = (f>>1)*16 + (lane&15)

__global__ void wprep(const float* __restrict__ convW1, const float* __restrict__ convW2,
                      ushort* __restrict__ wf) {
  const int wi = blockIdx.x;  // 0..5 = layer*2 + which
  const int layer = wi >> 1, which = wi & 1;
  const float* W = (which ? convW2 : convW1) + layer * 4096;
  const int t = threadIdx.x;  // 0..511
  const int f = t >> 6, lane = t & 63;
  const int ct = f >> 1, ks = f & 1;
  const int n = ct * 16 + (lane & 15);
  const int k0 = ks * 32 + ((lane >> 4) << 3);
  ushort hi[8], lo[8];
#pragma unroll
  for (int v = 0; v < 8; ++v) {
    float w = W[(k0 + v) * 64 + n];
    ushort h = bf16_rne(w);
    hi[v] = h;
    lo[v] = bf16_rne(w - bf16_tof(h));
  }
  ushort* base = wf + layer * 16384 + which * 8192;
  *(uint4*)(base + f * 512 + lane * 8) = *(uint4*)hi;
  *(uint4*)(base + 4096 + f * 512 + lane * 8) = *(uint4*)lo;
}

// ---------------- CSR build (XCD-partitioned writes) ----------------

__global__ void hist_part(const int* __restrict__ dst, int* __restrict__ deg) {
  const int p = blockIdx.x & 7;
  const int lo = p * NPART, hi = lo + NPART;
  const int stride = (gridDim.x >> 3) * 256;
  for (int e = (blockIdx.x >> 3) * 256 + threadIdx.x; e < N_EDGES; e += stride) {
    int d = dst[e];
    if (d >= lo && d < hi) atomicAdd(&deg[d], 1);
  }
}

__global__ void scan_blocks(const int* __restrict__ deg, int* __restrict__ bsum) {
  __shared__ int sd[SCAN_B];
  int i = blockIdx.x * SCAN_B + threadIdx.x;
  sd[threadIdx.x] = (i < N_NODES) ? deg[i] : 0;
  __syncthreads();
  for (int off = SCAN_B / 2; off > 0; off >>= 1) {
    if (threadIdx.x < off) sd[threadIdx.x] += sd[threadIdx.x + off];
    __syncthreads();
  }
  if (threadIdx.x == 0) bsum[blockIdx.x] = sd[0];
}

__global__ void scan_mid(int* __restrict__ bsum) {
  __shared__ int s[256];
  int t = threadIdx.x;
  if (t < NB_SCAN) s[t] = bsum[t];
  __syncthreads();
  if (t == 0) {
    int run = 0;
    for (int i = 0; i < NB_SCAN; ++i) { int v = s[i]; s[i] = run; run += v; }
  }
  __syncthreads();
  if (t < NB_SCAN) bsum[t] = s[t];
}

__global__ void scan_final(const int* __restrict__ deg, const int* __restrict__ bsum,
                           int* __restrict__ rs, int* __restrict__ cur) {
  __shared__ int sd[SCAN_B];
  int i = blockIdx.x * SCAN_B + threadIdx.x;
  int v = (i < N_NODES) ? deg[i] : 0;
  sd[threadIdx.x] = v;
  __syncthreads();
  for (int off = 1; off < SCAN_B; off <<= 1) {
    int add = (threadIdx.x >= off) ? sd[threadIdx.x - off] : 0;
    __syncthreads();
    sd[threadIdx.x] += add;
    __syncthreads();
  }
  if (i < N_NODES) {
    int ex = bsum[blockIdx.x] + sd[threadIdx.x] - v;
    rs[i] = ex;
    cur[i] = ex;
  }
  if (i == 0) rs[N_NODES] = N_EDGES;
}

__global__ void fill_part(const int* __restrict__ src, const int* __restrict__ dst,
                          int* __restrict__ cur, int* __restrict__ csr) {
  const int p = blockIdx.x & 7;
  const int lo = p * NPART, hi = lo + NPART;
  const int stride = (gridDim.x >> 3) * 256;
  for (int e = (blockIdx.x >> 3) * 256 + threadIdx.x; e < N_EDGES; e += stride) {
    int d = dst[e];
    if (d >= lo && d < hi) {
      int pos = atomicAdd(&cur[d], 1);
      csr[pos] = src[e];
    }
  }
}

// ---------------- GIN aggregation: out[n] = bf16( h[n] + sum h[csr[e]] ) ----------------

__global__ __launch_bounds__(256) void agg_bf16(
    const unsigned* __restrict__ hin, const int* __restrict__ csr,
    const int* __restrict__ rs, unsigned* __restrict__ hout) {
  const int t = threadIdx.x;
  const int hw = t >> 5, hl = t & 31;
  const int node = blockIdx.x * 8 + hw;
  float2 a = unpack2(hin[node * 32 + hl]);  // self term
  int e = rs[node];
  const int e1 = rs[node + 1];
  for (; e + 4 <= e1; e += 4) {
    int s0 = csr[e], s1 = csr[e + 1], s2 = csr[e + 2], s3 = csr[e + 3];
    float2 v0 = unpack2(hin[s0 * 32 + hl]);
    float2 v1 = unpack2(hin[s1 * 32 + hl]);
    float2 v2 = unpack2(hin[s2 * 32 + hl]);
    float2 v3 = unpack2(hin[s3 * 32 + hl]);
    a.x += v0.x + v1.x; a.y += v0.y + v1.y;
    a.x += v2.x + v3.x; a.y += v2.y + v3.y;
  }
  for (; e < e1; ++e) {
    float2 v = unpack2(hin[csr[e] * 32 + hl]);
    a.x += v.x; a.y += v.y;
  }
  hout[node * 32 + hl] = pack2(a.x, a.y);
}

// ---------------- MFMA MLP (bf16, 4 tiles/wave pipelined) ----------------
// Aout = relu(Ain@W1+b1)@W2+b2. Weights hi/lo in LDS (staged once per block);
// each wave loops 4 tiles (stride 784), prefetching the next tile's A-fragments
// before computing the current one (global latency hides under MFMA+transpose).
// A-frag: lane row=lane&15, k=(ks*32)+(lane>>4)*8+v. C/D: col=lane&15, row=(lane>>4)*4+j.

template <int FINAL>
__global__ __launch_bounds__(256, 2) void mlp_bf16(
    const unsigned* __restrict__ Ain,   // bf16 rows
    unsigned* __restrict__ Aout,        // bf16 rows (FINAL: unused)
    const ushort* __restrict__ wfL,     // layer base (16384 ushorts)
    const float* __restrict__ b1, const float* __restrict__ b2,
    const int* __restrict__ batch, unsigned* __restrict__ gU) {
  __shared__ ushort Wl[16384];       // 32KB: W1hi@0 W1lo@8KB W2hi@16KB W2lo@24KB (bytes)
  __shared__ ushort tb[4][16 * 68];  // per-wave transpose buf
  const int t = threadIdx.x;
  const int w = t >> 6, lane = t & 63;
  const int m = lane & 15, g = lane >> 4;
  ushort* tw = tb[w];

  // ---- stage all weights (32KB) once per block ----
  {
    const uint4* s = (const uint4*)wfL;
    uint4* d = (uint4*)Wl;
#pragma unroll
    for (int i = 0; i < 8; ++i) d[t + 256 * i] = s[t + 256 * i];
  }

  // ---- preload first tile's A fragments ----
  int tile = blockIdx.x * 4 + w;  // wave_gid in 0..783
  bool act = (tile < NT);
  bf16x8 a0 = {}, a1 = {};
  if (act) {
    const ushort* Ar = (const ushort*)Ain + (size_t)(tile * 16 + m) * 64;
    a0 = *(const bf16x8*)(Ar + g * 8);
    a1 = *(const bf16x8*)(Ar + 32 + g * 8);
  }
  __syncthreads();  // weights ready

  const char* wb = (const char*)Wl + lane * 16;
  const float bv10 = b1[m], bv11 = b1[16 + m], bv12 = b1[32 + m], bv13 = b1[48 + m];
  const float bv20 = b2[m], bv21 = b2[16 + m], bv22 = b2[32 + m], bv23 = b2[48 + m];

#define LDW(off) (*(const bf16x8*)(wb + (off)))

#pragma unroll
  for (int it = 0; it < 4; ++it) {
    // ---- prefetch next tile's A (issues before current compute) ----
    const int ntile = tile + 4 * MLP_BLOCKS;
    const bool nact = (it < 3) && (ntile < NT);
    bf16x8 na0 = {}, na1 = {};
    if (nact) {
      const ushort* Ar = (const ushort*)Ain + (size_t)(ntile * 16 + m) * 64;
      na0 = *(const bf16x8*)(Ar + g * 8);
      na1 = *(const bf16x8*)(Ar + 32 + g * 8);
    }

    if (act) {
      // ---- GEMM1: c = A@(W1hi + W1lo) ----
      f32x4 c0 = {0.f, 0.f, 0.f, 0.f}, c1 = c0, c2 = c0, c3 = c0;
#define G1(ct, cc)                                        \
      cc = MFMA16(a0, LDW((2 * ct + 0) * 1024), cc);      \
      cc = MFMA16(a1, LDW((2 * ct + 1) * 1024), cc);      \
      cc = MFMA16(a0, LDW(8192 + (2 * ct + 0) * 1024), cc); \
      cc = MFMA16(a1, LDW(8192 + (2 * ct + 1) * 1024), cc);
      G1(0, c0) G1(1, c1) G1(2, c2) G1(3, c3)
#undef G1

      // ---- bias + relu -> bf16 transpose (C/D -> A-frag layout) ----
#define WRT(cc, ct, bv)                                                     \
      tw[(g * 4 + 0) * 68 + ct * 16 + m] = bf16_rne(fmaxf(cc[0] + bv, 0.f)); \
      tw[(g * 4 + 1) * 68 + ct * 16 + m] = bf16_rne(fmaxf(cc[1] + bv, 0.f)); \
      tw[(g * 4 + 2) * 68 + ct * 16 + m] = bf16_rne(fmaxf(cc[2] + bv, 0.f)); \
      tw[(g * 4 + 3) * 68 + ct * 16 + m] = bf16_rne(fmaxf(cc[3] + bv, 0.f));
      WRT(c0, 0, bv10) WRT(c1, 1, bv11) WRT(c2, 2, bv12) WRT(c3, 3, bv13)
#undef WRT
      bf16x8 h0 = *(const bf16x8*)(tw + m * 68 + g * 8);
      bf16x8 h1 = *(const bf16x8*)(tw + m * 68 + 32 + g * 8);

      // ---- GEMM2: c = H@(W2hi + W2lo) ----
      c0 = (f32x4){0.f, 0.f, 0.f, 0.f}; c1 = c0; c2 = c0; c3 = c0;
#define G2(ct, cc)                                         \
      cc = MFMA16(h0, LDW(16384 + (2 * ct + 0) * 1024), cc); \
      cc = MFMA16(h1, LDW(16384 + (2 * ct + 1) * 1024), cc); \
      cc = MFMA16(h0, LDW(24576 + (2 * ct + 0) * 1024), cc); \
      cc = MFMA16(h1, LDW(24576 + (2 * ct + 1) * 1024), cc);
      G2(0, c0) G2(1, c1) G2(2, c2) G2(3, c3)
#undef G2

      if (FINAL) {
        int b40 = batch[tile * 16 + g * 4 + 0];
        int b41 = batch[tile * 16 + g * 4 + 1];
        int b42 = batch[tile * 16 + g * 4 + 2];
        int b43 = batch[tile * 16 + g * 4 + 3];
#define PM(cc, ct, bv)                                          \
        atomicMax(&gU[b40 * 64 + ct * 16 + m], mapf(cc[0] + bv)); \
        atomicMax(&gU[b41 * 64 + ct * 16 + m], mapf(cc[1] + bv)); \
        atomicMax(&gU[b42 * 64 + ct * 16 + m], mapf(cc[2] + bv)); \
        atomicMax(&gU[b43 * 64 + ct * 16 + m], mapf(cc[3] + bv));
        PM(c0, 0, bv20) PM(c1, 1, bv21) PM(c2, 2, bv22) PM(c3, 3, bv23)
#undef PM
      } else {
        // bias -> bf16 into tw, then fully-coalesced stores (lane l owns 32B chunk l)
#define WRO(cc, ct, bv)                                          \
        tw[(g * 4 + 0) * 68 + ct * 16 + m] = bf16_rne(cc[0] + bv); \
        tw[(g * 4 + 1) * 68 + ct * 16 + m] = bf16_rne(cc[1] + bv); \
        tw[(g * 4 + 2) * 68 + ct * 16 + m] = bf16_rne(cc[2] + bv); \
        tw[(g * 4 + 3) * 68 + ct * 16 + m] = bf16_rne(cc[3] + bv);
        WRO(c0, 0, bv20) WRO(c1, 1, bv21) WRO(c2, 2, bv22) WRO(c3, 3, bv23)
#undef WRO
        const int r = lane >> 2, q = lane & 3;
        uint4 v0 = *(const uint4*)(tw + r * 68 + q * 16);
        uint4 v1 = *(const uint4*)(tw + r * 68 + q * 16 + 8);
        ushort* Ao = (ushort*)Aout + (size_t)tile * 1024;
        *(uint4*)(Ao + lane * 16) = v0;
        *(uint4*)(Ao + lane * 16 + 8) = v1;
      }
    }

    a0 = na0; a1 = na1; tile = ntile; act = nact;
  }
#undef LDW
}

// ---------------- pooling init + head ----------------

__global__ void init_g(unsigned* __restrict__ gU) {
  int i = blockIdx.x * blockDim.x + threadIdx.x;
  if (i < N_GRAPHS * D) gU[i] = 0x007FFFFFu;  // mapf(-inf)
}

__global__ void head_kernel(const unsigned* __restrict__ gU,
                            const float* __restrict__ fcW1, const float* __restrict__ fcb1,
                            const float* __restrict__ fcW2, const float* __restrict__ fcb2,
                            float* __restrict__ out) {
  __shared__ float gbuf[64];
  __shared__ float hid[64];
  __shared__ float logit[N_CLASSES];
  __shared__ float red[2];
  const int gi = blockIdx.x;
  const int t = threadIdx.x;

  gbuf[t] = unmapf(gU[gi * D + t]);
  __syncthreads();

  float a = fcb1[t];
#pragma unroll
  for (int k = 0; k < 64; ++k) a = fmaf(gbuf[k], fcW1[k * 64 + t], a);
  hid[t] = fmaxf(a, 0.0f);
  __syncthreads();

  if (t < N_CLASSES) {
    float l = fcb2[t];
#pragma unroll
    for (int k = 0; k < 64; ++k) l = fmaf(hid[k], fcW2[k * N_CLASSES + t], l);
    logit[t] = l;
  }
  __syncthreads();

  if (t == 0) {
    float mx = logit[0];
    for (int i = 1; i < N_CLASSES; ++i) mx = fmaxf(mx, logit[i]);
    float s = 0.0f;
    for (int i = 0; i < N_CLASSES; ++i) s += expf(logit[i] - mx);
    red[0] = mx;
    red[1] = logf(s);
  }
  __syncthreads();

  if (t < N_CLASSES) out[gi * N_CLASSES + t] = logit[t] - red[0] - red[1];
}

// ---------------- launch ----------------

extern "C" void kernel_launch(void* const* d_in, const int* in_sizes, int n_in,
                              void* d_out, int out_size, void* d_ws, size_t ws_size,
                              hipStream_t stream) {
  const float* x      = (const float*)d_in[0];
  const float* convW1 = (const float*)d_in[1];
  const float* convb1 = (const float*)d_in[2];
  const float* convW2 = (const float*)d_in[3];
  const float* convb2 = (const float*)d_in[4];
  const float* fcW1   = (const float*)d_in[5];
  const float* fcb1   = (const float*)d_in[6];
  const float* fcW2   = (const float*)d_in[7];
  const float* fcb2   = (const float*)d_in[8];
  const int*   edge   = (const int*)d_in[9];
  const int*   batch  = (const int*)d_in[10];
  float* out = (float*)d_out;

  const int* src = edge;
  const int* dst = edge + N_EDGES;

  // workspace layout (~23 MB)
  unsigned* xb  = (unsigned*)d_ws;                  // 6.4 MB bf16 h
  unsigned* hbA = xb + (size_t)N_NODES * 32;        // 6.4 MB bf16 (agg out)
  unsigned* hbB = hbA + (size_t)N_NODES * 32;       // 6.4 MB bf16 (mlp out)
  unsigned* gU  = hbB + (size_t)N_NODES * 32;       // 131 KB
  int* rs  = (int*)(gU + N_GRAPHS * D);             // 200 KB
  int* csr = rs + N_NODES + 1;                      // 3.2 MB
  ushort* wf = (ushort*)(csr + N_EDGES);            // 96 KB
  // deg/cur/bsum overlap hbB (dead before hbB is first written by mlp #1)
  int* deg  = (int*)hbB;
  int* cur  = deg + N_NODES;
  int* bsum = cur + N_NODES;

  // ---- prep: x->bf16, W fragments, pool init ----
  to_bf16<<<(N_NODES * 16) / 256, 256, 0, stream>>>(x, xb);
  wprep<<<6, 512, 0, stream>>>(convW1, convW2, wf);
  init_g<<<(N_GRAPHS * D + 255) / 256, 256, 0, stream>>>(gU);

  // ---- CSR build (dst-indexed, XCD-partitioned writes) ----
  hipMemsetAsync(deg, 0, N_NODES * sizeof(int), stream);
  hist_part<<<2048, 256, 0, stream>>>(dst, deg);
  scan_blocks<<<NB_SCAN, SCAN_B, 0, stream>>>(deg, bsum);
  scan_mid<<<1, 256, 0, stream>>>(bsum);
  scan_final<<<NB_SCAN, SCAN_B, 0, stream>>>(deg, bsum, rs, cur);
  fill_part<<<2048, 256, 0, stream>>>(src, dst, cur, csr);

  // ---- 3 GIN layers: agg X->T, mlp T->Y, swap ----
  const int AGG_B = N_NODES / 8;    // 6250
  agg_bf16<<<AGG_B, 256, 0, stream>>>(xb, csr, rs, hbA);
  mlp_bf16<0><<<MLP_BLOCKS, 256, 0, stream>>>(hbA, hbB, wf, convb1, convb2, batch, gU);
  agg_bf16<<<AGG_B, 256, 0, stream>>>(hbB, csr, rs, hbA);
  mlp_bf16<0><<<MLP_BLOCKS, 256, 0, stream>>>(hbA, xb, wf + 16384, convb1 + 64,
                                              convb2 + 64, batch, gU);
  agg_bf16<<<AGG_B, 256, 0, stream>>>(xb, csr, rs, hbA);
  mlp_bf16<1><<<MLP_BLOCKS, 256, 0, stream>>>(hbA, nullptr, wf + 32768, convb1 + 128,
                                              convb2 + 128, batch, gU);

  // ---- FC head + log_softmax ----
  head_kernel<<<N_GRAPHS, 64, 0, stream>>>(gU, fcW1, fcb1, fcW2, fcb2, out);
}